// Round 9
// baseline (529.502 us; speedup 1.0000x reference)
//
#include <hip/hip_runtime.h>
#include <hip/hip_bf16.h>
#include <hip/hip_cooperative_groups.h>

namespace cg = cooperative_groups;

typedef __hip_bfloat16 bf16;

#define N_NODES 16384
#define D_IN    128
#define HID     64
#define HEADS   4
#define F1      256   // HEADS*HID
#define SEQ     128
#define SLOTS   64    // fixed CSR capacity per node (P(deg>64) ~ 1e-12 for this graph)
#define GRIDB   512   // cooperative grid: 2 blocks/CU required (ample margin)

__device__ __forceinline__ float wave_sum(float v) {
    #pragma unroll
    for (int o = 32; o > 0; o >>= 1) v += __shfl_xor(v, o, 64);
    return v;
}
__device__ __forceinline__ float wave_max(float v) {
    #pragma unroll
    for (int o = 32; o > 0; o >>= 1) v = fmaxf(v, __shfl_xor(v, o, 64));
    return v;
}
__device__ __forceinline__ float lrelu(float v) { return v > 0.f ? v : 0.2f * v; }
__device__ __forceinline__ float rdlane(float v, int l) {
    return __uint_as_float(__builtin_amdgcn_readlane(__float_as_uint(v), l));
}

// ==================== cooperative mega-kernel ====================
__global__ __launch_bounds__(256, 2) void k_mega(
        const int* __restrict__ ei, int E, int Etot,
        const float* __restrict__ x, const float* __restrict__ pe,
        const float* __restrict__ W1,
        const float* __restrict__ a_src1, const float* __restrict__ a_dst1,
        const float* __restrict__ b1,
        const float* __restrict__ W2,
        const float* __restrict__ a_src2, const float* __restrict__ a_dst2,
        const float* __restrict__ b2v,
        int* __restrict__ cnt, int* __restrict__ esrc,
        bf16* __restrict__ h, float* __restrict__ as1, float* __restrict__ ad1,
        float* __restrict__ h1,
        bf16* __restrict__ h2, float* __restrict__ as2, float* __restrict__ ad2,
        float* __restrict__ out) {
    cg::grid_group grid = cg::this_grid();
    int tid  = threadIdx.x;
    int lane = tid & 63, wv = tid >> 6;
    int gtid = blockIdx.x * 256 + tid;
    const int NTH = GRIDB * 256;

    __shared__ float hs[16][256];   // used in phase 4

    // ---------- phase 0: zero cnt ----------
    for (int i = gtid; i < N_NODES; i += NTH) cnt[i] = 0;
    grid.sync();

    // ---------- phase 1: edge scatter ----------
    for (int e = gtid; e < Etot; e += NTH) {
        int s, d;
        if (e < E) { s = ei[e]; d = ei[E + e]; }
        else       { s = e - E; d = s; }
        int pos = atomicAdd(&cnt[d], 1);
        if (pos < SLOTS) esrc[d * SLOTS + pos] = s;
    }
    grid.sync();

    // ---------- phase 2: gemm1 (+PE, +logits); 16 rows/tile, 4 rows/wave ----------
    {
        int j4 = lane * 4;
        float4 asv = *(const float4*)(a_src1 + j4);
        float4 adv = *(const float4*)(a_dst1 + j4);
        const float4* Wv = (const float4*)W1;   // Wv[k*64 + lane] == W1[k*256 + lane*4]
        for (int bb = blockIdx.x; bb < N_NODES / 16; bb += GRIDB) {
            int base = bb * 16;
            float2 xr[4];
            #pragma unroll
            for (int i = 0; i < 4; i++) {
                int row = base + wv * 4 + i;
                float2 xa  = *(const float2*)(x  + (size_t)row * 128 + 2 * lane);
                float2 pea = *(const float2*)(pe + (size_t)(row & (SEQ - 1)) * 128 + 2 * lane);
                xr[i].x = xa.x * 11.313708499f + pea.x;
                xr[i].y = xa.y * 11.313708499f + pea.y;
            }
            float acc[4][4] = {};
            #pragma unroll 4
            for (int k2 = 0; k2 < 64; k2++) {
                float4 w0 = Wv[(size_t)(2 * k2) * 64 + lane];
                float4 w1 = Wv[(size_t)(2 * k2 + 1) * 64 + lane];
                #pragma unroll
                for (int i = 0; i < 4; i++) {
                    float a0 = rdlane(xr[i].x, k2);
                    float a1 = rdlane(xr[i].y, k2);
                    acc[i][0] += a0 * w0.x + a1 * w1.x;
                    acc[i][1] += a0 * w0.y + a1 * w1.y;
                    acc[i][2] += a0 * w0.z + a1 * w1.z;
                    acc[i][3] += a0 * w0.w + a1 * w1.w;
                }
            }
            #pragma unroll
            for (int i = 0; i < 4; i++) {
                int row = base + wv * 4 + i;
                union { bf16 b[4]; ushort4 u; } cv;
                cv.b[0] = __float2bfloat16(acc[i][0]);
                cv.b[1] = __float2bfloat16(acc[i][1]);
                cv.b[2] = __float2bfloat16(acc[i][2]);
                cv.b[3] = __float2bfloat16(acc[i][3]);
                *(ushort4*)(h + (size_t)row * 256 + j4) = cv.u;
                float vs = acc[i][0] * asv.x + acc[i][1] * asv.y + acc[i][2] * asv.z + acc[i][3] * asv.w;
                float vd = acc[i][0] * adv.x + acc[i][1] * adv.y + acc[i][2] * adv.z + acc[i][3] * adv.w;
                #pragma unroll
                for (int o = 1; o < 16; o <<= 1) {
                    vs += __shfl_xor(vs, o);
                    vd += __shfl_xor(vd, o);
                }
                if ((lane & 15) == 0) {
                    as1[row * 4 + (lane >> 4)] = vs;
                    ad1[row * 4 + (lane >> 4)] = vd;
                }
            }
        }
    }
    grid.sync();

    // ---------- phase 3: agg1; block = node, wave = head ----------
    {
        int eg = lane >> 3;   // edge slot within octet group
        int cg_ = lane & 7;   // channel group (8 channels, 16 B)
        const bf16* hbase = h + (size_t)wv * 64 + cg_ * 8;
        for (int d = blockIdx.x; d < N_NODES; d += GRIDB) {
            int beg = d * SLOTS;
            int deg = min(cnt[d], SLOTS);
            float adw = ad1[d * 4 + wv];

            int s = 0; float ev = -1e30f;
            if (lane < deg) {
                s = esrc[beg + lane];
                ev = lrelu(as1[s * 4 + wv] + adw);
            }
            float mx = wave_max(ev);
            float t = (lane < deg) ? __expf(ev - mx) : 0.f;
            float den = wave_sum(t);

            float acc[8] = {0, 0, 0, 0, 0, 0, 0, 0};
            for (int sub = 0; sub < deg; sub += 32) {
                uint4 u[4]; float te[4];
                #pragma unroll
                for (int q = 0; q < 4; q++) {
                    int e = sub + q * 8;
                    int se = __shfl(s, e + eg);
                    te[q] = __shfl(t, e + eg);
                    if (e < deg) u[q] = *(const uint4*)(hbase + (size_t)se * 256);
                    else         u[q] = make_uint4(0, 0, 0, 0);
                }
                #pragma unroll
                for (int q = 0; q < 4; q++) {
                    acc[0] += te[q] * __uint_as_float(u[q].x << 16);
                    acc[1] += te[q] * __uint_as_float(u[q].x & 0xffff0000u);
                    acc[2] += te[q] * __uint_as_float(u[q].y << 16);
                    acc[3] += te[q] * __uint_as_float(u[q].y & 0xffff0000u);
                    acc[4] += te[q] * __uint_as_float(u[q].z << 16);
                    acc[5] += te[q] * __uint_as_float(u[q].z & 0xffff0000u);
                    acc[6] += te[q] * __uint_as_float(u[q].w << 16);
                    acc[7] += te[q] * __uint_as_float(u[q].w & 0xffff0000u);
                }
            }
            #pragma unroll
            for (int j = 0; j < 8; j++) {
                acc[j] += __shfl_xor(acc[j], 8);
                acc[j] += __shfl_xor(acc[j], 16);
                acc[j] += __shfl_xor(acc[j], 32);
            }
            if (lane < 8) {
                float inv = 1.f / (den + 1e-16f);
                int cbase = wv * 64 + lane * 8;
                float o[8];
                #pragma unroll
                for (int j = 0; j < 8; j++) {
                    float v = acc[j] * inv + b1[cbase + j];
                    o[j] = v > 0.f ? v : (__expf(v) - 1.f);   // elu
                }
                float4* dst = (float4*)(h1 + (size_t)d * 256 + cbase);
                dst[0] = make_float4(o[0], o[1], o[2], o[3]);
                dst[1] = make_float4(o[4], o[5], o[6], o[7]);
            }
        }
    }
    grid.sync();

    // ---------- phase 4: gemm2 (+logits); 16 rows/tile ----------
    {
        float asj = a_src2[lane], adj = a_dst2[lane];
        for (int bb = blockIdx.x; bb < N_NODES / 16; bb += GRIDB) {
            int base = bb * 16;
            const float4* srcv = (const float4*)(h1 + (size_t)base * 256);
            float4* dstv = (float4*)&hs[0][0];
            #pragma unroll
            for (int i = 0; i < 4; i++) dstv[tid + i * 256] = srcv[tid + i * 256];
            __syncthreads();

            float acc[4] = {0, 0, 0, 0};
            const float* hrow = &hs[wv * 4][0];
            #pragma unroll 4
            for (int k = 0; k < 256; k++) {
                float w = W2[k * 64 + lane];
                #pragma unroll
                for (int r = 0; r < 4; r++) acc[r] += hrow[r * 256 + k] * w;
            }
            #pragma unroll
            for (int r = 0; r < 4; r++) {
                int n = base + wv * 4 + r;
                h2[(size_t)n * 64 + lane] = __float2bfloat16(acc[r]);
                float va = wave_sum(acc[r] * asj);
                float vd = wave_sum(acc[r] * adj);
                if (lane == 0) { as2[n] = va; ad2[n] = vd; }
            }
            __syncthreads();   // hs reused next iteration
        }
    }
    grid.sync();

    // ---------- phase 5: agg2 -> out; wave = node ----------
    {
        int eg = lane >> 3;
        int cg_ = lane & 7;
        const bf16* hbase = h2 + cg_ * 8;
        for (int d = blockIdx.x * 4 + wv; d < N_NODES; d += GRIDB * 4) {
            int beg = d * SLOTS;
            int deg = min(cnt[d], SLOTS);
            float adw = ad2[d];

            int s = 0; float ev = -1e30f;
            if (lane < deg) {
                s = esrc[beg + lane];
                ev = lrelu(as2[s] + adw);
            }
            float mx = wave_max(ev);
            float t = (lane < deg) ? __expf(ev - mx) : 0.f;
            float den = wave_sum(t);

            float acc[8] = {0, 0, 0, 0, 0, 0, 0, 0};
            for (int sub = 0; sub < deg; sub += 32) {
                uint4 u[4]; float te[4];
                #pragma unroll
                for (int q = 0; q < 4; q++) {
                    int e = sub + q * 8;
                    int se = __shfl(s, e + eg);
                    te[q] = __shfl(t, e + eg);
                    if (e < deg) u[q] = *(const uint4*)(hbase + (size_t)se * 64);
                    else         u[q] = make_uint4(0, 0, 0, 0);
                }
                #pragma unroll
                for (int q = 0; q < 4; q++) {
                    acc[0] += te[q] * __uint_as_float(u[q].x << 16);
                    acc[1] += te[q] * __uint_as_float(u[q].x & 0xffff0000u);
                    acc[2] += te[q] * __uint_as_float(u[q].y << 16);
                    acc[3] += te[q] * __uint_as_float(u[q].y & 0xffff0000u);
                    acc[4] += te[q] * __uint_as_float(u[q].z << 16);
                    acc[5] += te[q] * __uint_as_float(u[q].z & 0xffff0000u);
                    acc[6] += te[q] * __uint_as_float(u[q].w << 16);
                    acc[7] += te[q] * __uint_as_float(u[q].w & 0xffff0000u);
                }
            }
            #pragma unroll
            for (int j = 0; j < 8; j++) {
                acc[j] += __shfl_xor(acc[j], 8);
                acc[j] += __shfl_xor(acc[j], 16);
                acc[j] += __shfl_xor(acc[j], 32);
            }
            if (lane < 8) {
                float inv = 1.f / (den + 1e-16f);
                int cbase = lane * 8;
                float o[8];
                #pragma unroll
                for (int j = 0; j < 8; j++) o[j] = acc[j] * inv + b2v[cbase + j];
                float4* dst = (float4*)(out + (size_t)d * 64 + cbase);
                dst[0] = make_float4(o[0], o[1], o[2], o[3]);
                dst[1] = make_float4(o[4], o[5], o[6], o[7]);
            }
        }
    }
}

// ==================== fallback: round-6 known-good kernels ====================

__global__ __launch_bounds__(256) void k_zero(int4* p) {
    p[blockIdx.x * 256 + threadIdx.x] = make_int4(0, 0, 0, 0);
}

__global__ __launch_bounds__(256) void k_scatter(const int* __restrict__ ei, int E, int Etot,
                                                 int* __restrict__ cnt,
                                                 int* __restrict__ esrc) {
    int e = blockIdx.x * 256 + threadIdx.x;
    if (e >= Etot) return;
    int s, d;
    if (e < E) { s = ei[e]; d = ei[E + e]; }
    else       { s = e - E; d = s; }
    int pos = atomicAdd(&cnt[d], 1);
    if (pos < SLOTS) esrc[d * SLOTS + pos] = s;
}

__global__ __launch_bounds__(256) void k_gemm1(const float* __restrict__ x,
                                               const float* __restrict__ pe,
                                               const float* __restrict__ W1,
                                               const float* __restrict__ a_src1,
                                               const float* __restrict__ a_dst1,
                                               bf16* __restrict__ h,
                                               float* __restrict__ as1,
                                               float* __restrict__ ad1) {
    int tid = threadIdx.x, lane = tid & 63, wv = tid >> 6;
    int base = blockIdx.x * 16;
    int j4 = lane * 4;
    float2 xr[4];
    #pragma unroll
    for (int i = 0; i < 4; i++) {
        int row = base + wv * 4 + i;
        float2 xa  = *(const float2*)(x  + (size_t)row * 128 + 2 * lane);
        float2 pea = *(const float2*)(pe + (size_t)(row & (SEQ - 1)) * 128 + 2 * lane);
        xr[i].x = xa.x * 11.313708499f + pea.x;
        xr[i].y = xa.y * 11.313708499f + pea.y;
    }
    float acc[4][4] = {};
    const float4* Wv = (const float4*)W1;
    #pragma unroll 4
    for (int k2 = 0; k2 < 64; k2++) {
        float4 w0 = Wv[(size_t)(2 * k2) * 64 + lane];
        float4 w1 = Wv[(size_t)(2 * k2 + 1) * 64 + lane];
        #pragma unroll
        for (int i = 0; i < 4; i++) {
            float a0 = rdlane(xr[i].x, k2);
            float a1 = rdlane(xr[i].y, k2);
            acc[i][0] += a0 * w0.x + a1 * w1.x;
            acc[i][1] += a0 * w0.y + a1 * w1.y;
            acc[i][2] += a0 * w0.z + a1 * w1.z;
            acc[i][3] += a0 * w0.w + a1 * w1.w;
        }
    }
    float4 asv = *(const float4*)(a_src1 + j4);
    float4 adv = *(const float4*)(a_dst1 + j4);
    #pragma unroll
    for (int i = 0; i < 4; i++) {
        int row = base + wv * 4 + i;
        union { bf16 b[4]; ushort4 u; } cv;
        cv.b[0] = __float2bfloat16(acc[i][0]);
        cv.b[1] = __float2bfloat16(acc[i][1]);
        cv.b[2] = __float2bfloat16(acc[i][2]);
        cv.b[3] = __float2bfloat16(acc[i][3]);
        *(ushort4*)(h + (size_t)row * 256 + j4) = cv.u;
        float vs = acc[i][0] * asv.x + acc[i][1] * asv.y + acc[i][2] * asv.z + acc[i][3] * asv.w;
        float vd = acc[i][0] * adv.x + acc[i][1] * adv.y + acc[i][2] * adv.z + acc[i][3] * adv.w;
        #pragma unroll
        for (int o = 1; o < 16; o <<= 1) {
            vs += __shfl_xor(vs, o);
            vd += __shfl_xor(vd, o);
        }
        if ((lane & 15) == 0) {
            as1[row * 4 + (lane >> 4)] = vs;
            ad1[row * 4 + (lane >> 4)] = vd;
        }
    }
}

__global__ __launch_bounds__(256) void k_agg1(const int* __restrict__ cnt,
                                              const int* __restrict__ esrc,
                                              const bf16* __restrict__ h,
                                              const float* __restrict__ as1,
                                              const float* __restrict__ ad1,
                                              const float* __restrict__ b1,
                                              float* __restrict__ h1) {
    int d = blockIdx.x;
    int tid = threadIdx.x, lane = tid & 63, wv = tid >> 6;
    int beg = d * SLOTS;
    int deg = min(cnt[d], SLOTS);
    float adw = ad1[d * 4 + wv];
    int eg = lane >> 3, cg_ = lane & 7;
    const bf16* hbase = h + (size_t)wv * 64 + cg_ * 8;

    int s = 0; float ev = -1e30f;
    if (lane < deg) {
        s = esrc[beg + lane];
        ev = lrelu(as1[s * 4 + wv] + adw);
    }
    float mx = wave_max(ev);
    float t = (lane < deg) ? __expf(ev - mx) : 0.f;
    float den = wave_sum(t);

    float acc[8] = {0, 0, 0, 0, 0, 0, 0, 0};
    for (int sub = 0; sub < deg; sub += 32) {
        uint4 u[4]; float te[4];
        #pragma unroll
        for (int q = 0; q < 4; q++) {
            int e = sub + q * 8;
            int se = __shfl(s, e + eg);
            te[q] = __shfl(t, e + eg);
            if (e < deg) u[q] = *(const uint4*)(hbase + (size_t)se * 256);
            else         u[q] = make_uint4(0, 0, 0, 0);
        }
        #pragma unroll
        for (int q = 0; q < 4; q++) {
            acc[0] += te[q] * __uint_as_float(u[q].x << 16);
            acc[1] += te[q] * __uint_as_float(u[q].x & 0xffff0000u);
            acc[2] += te[q] * __uint_as_float(u[q].y << 16);
            acc[3] += te[q] * __uint_as_float(u[q].y & 0xffff0000u);
            acc[4] += te[q] * __uint_as_float(u[q].z << 16);
            acc[5] += te[q] * __uint_as_float(u[q].z & 0xffff0000u);
            acc[6] += te[q] * __uint_as_float(u[q].w << 16);
            acc[7] += te[q] * __uint_as_float(u[q].w & 0xffff0000u);
        }
    }
    #pragma unroll
    for (int j = 0; j < 8; j++) {
        acc[j] += __shfl_xor(acc[j], 8);
        acc[j] += __shfl_xor(acc[j], 16);
        acc[j] += __shfl_xor(acc[j], 32);
    }
    if (lane < 8) {
        float inv = 1.f / (den + 1e-16f);
        int cbase = wv * 64 + lane * 8;
        float o[8];
        #pragma unroll
        for (int j = 0; j < 8; j++) {
            float v = acc[j] * inv + b1[cbase + j];
            o[j] = v > 0.f ? v : (__expf(v) - 1.f);
        }
        float4* dst = (float4*)(h1 + (size_t)d * 256 + cbase);
        dst[0] = make_float4(o[0], o[1], o[2], o[3]);
        dst[1] = make_float4(o[4], o[5], o[6], o[7]);
    }
}

__global__ __launch_bounds__(256) void k_gemm2(const float* __restrict__ h1,
                                               const float* __restrict__ W2,
                                               const float* __restrict__ a_src2,
                                               const float* __restrict__ a_dst2,
                                               bf16* __restrict__ h2,
                                               float* __restrict__ as2,
                                               float* __restrict__ ad2) {
    __shared__ float hs[16][256];
    int tid = threadIdx.x;
    int base = blockIdx.x * 16;
    const float4* srcv = (const float4*)(h1 + (size_t)base * 256);
    float4* dstv = (float4*)&hs[0][0];
    #pragma unroll
    for (int i = 0; i < 4; i++) dstv[tid + i * 256] = srcv[tid + i * 256];
    __syncthreads();
    int j = tid & 63, wv = tid >> 6;
    float acc[4] = {0, 0, 0, 0};
    const float* hrow = &hs[wv * 4][0];
    #pragma unroll 4
    for (int k = 0; k < 256; k++) {
        float w = W2[k * 64 + j];
        #pragma unroll
        for (int r = 0; r < 4; r++) acc[r] += hrow[r * 256 + k] * w;
    }
    float asj = a_src2[j], adj = a_dst2[j];
    #pragma unroll
    for (int r = 0; r < 4; r++) {
        int n = base + wv * 4 + r;
        h2[(size_t)n * 64 + j] = __float2bfloat16(acc[r]);
        float va = wave_sum(acc[r] * asj);
        float vd = wave_sum(acc[r] * adj);
        if (j == 0) { as2[n] = va; ad2[n] = vd; }
    }
}

__global__ __launch_bounds__(256) void k_agg2(const int* __restrict__ cnt,
                                              const int* __restrict__ esrc,
                                              const bf16* __restrict__ h2,
                                              const float* __restrict__ as2,
                                              const float* __restrict__ ad2,
                                              const float* __restrict__ b2v,
                                              float* __restrict__ out) {
    int tid = threadIdx.x, lane = tid & 63, wv = tid >> 6;
    int d = blockIdx.x * 4 + wv;
    int beg = d * SLOTS;
    int deg = min(cnt[d], SLOTS);
    float adw = ad2[d];
    int eg = lane >> 3, cg_ = lane & 7;
    const bf16* hbase = h2 + cg_ * 8;

    int s = 0; float ev = -1e30f;
    if (lane < deg) {
        s = esrc[beg + lane];
        ev = lrelu(as2[s] + adw);
    }
    float mx = wave_max(ev);
    float t = (lane < deg) ? __expf(ev - mx) : 0.f;
    float den = wave_sum(t);

    float acc[8] = {0, 0, 0, 0, 0, 0, 0, 0};
    for (int sub = 0; sub < deg; sub += 32) {
        uint4 u[4]; float te[4];
        #pragma unroll
        for (int q = 0; q < 4; q++) {
            int e = sub + q * 8;
            int se = __shfl(s, e + eg);
            te[q] = __shfl(t, e + eg);
            if (e < deg) u[q] = *(const uint4*)(hbase + (size_t)se * 64);
            else         u[q] = make_uint4(0, 0, 0, 0);
        }
        #pragma unroll
        for (int q = 0; q < 4; q++) {
            acc[0] += te[q] * __uint_as_float(u[q].x << 16);
            acc[1] += te[q] * __uint_as_float(u[q].x & 0xffff0000u);
            acc[2] += te[q] * __uint_as_float(u[q].y << 16);
            acc[3] += te[q] * __uint_as_float(u[q].y & 0xffff0000u);
            acc[4] += te[q] * __uint_as_float(u[q].z << 16);
            acc[5] += te[q] * __uint_as_float(u[q].z & 0xffff0000u);
            acc[6] += te[q] * __uint_as_float(u[q].w << 16);
            acc[7] += te[q] * __uint_as_float(u[q].w & 0xffff0000u);
        }
    }
    #pragma unroll
    for (int j = 0; j < 8; j++) {
        acc[j] += __shfl_xor(acc[j], 8);
        acc[j] += __shfl_xor(acc[j], 16);
        acc[j] += __shfl_xor(acc[j], 32);
    }
    if (lane < 8) {
        float inv = 1.f / (den + 1e-16f);
        int cbase = lane * 8;
        float o[8];
        #pragma unroll
        for (int j = 0; j < 8; j++) o[j] = acc[j] * inv + b2v[cbase + j];
        float4* dst = (float4*)(out + (size_t)d * 64 + cbase);
        dst[0] = make_float4(o[0], o[1], o[2], o[3]);
        dst[1] = make_float4(o[4], o[5], o[6], o[7]);
    }
}

extern "C" void kernel_launch(void* const* d_in, const int* in_sizes, int n_in,
                              void* d_out, int out_size, void* d_ws, size_t ws_size,
                              hipStream_t stream) {
    const float* x    = (const float*)d_in[0];
    const int*   ei   = (const int*)  d_in[1];
    const float* pe   = (const float*)d_in[2];
    const float* W1   = (const float*)d_in[3];
    const float* a_s1 = (const float*)d_in[4];
    const float* a_d1 = (const float*)d_in[5];
    const float* b1   = (const float*)d_in[6];
    const float* W2   = (const float*)d_in[7];
    const float* a_s2 = (const float*)d_in[8];
    const float* a_d2 = (const float*)d_in[9];
    const float* b2   = (const float*)d_in[10];

    const int E    = in_sizes[1] / 2;
    const int n    = N_NODES;
    const int Etot = E + n;

    // workspace carve-up (256B aligned)
    char* p = (char*)d_ws;
    auto alloc = [&](size_t bytes) -> void* {
        void* r = (void*)p;
        p += (bytes + 255) & ~(size_t)255;
        return r;
    };
    int*   cnt     = (int*)  alloc((size_t)n * 4);
    int*   esrc    = (int*)  alloc((size_t)n * SLOTS * 4);
    bf16*  h       = (bf16*) alloc((size_t)n * F1 * 2);
    float* as1     = (float*)alloc((size_t)n * HEADS * 4);
    float* ad1     = (float*)alloc((size_t)n * HEADS * 4);
    float* h1      = (float*)alloc((size_t)n * F1 * 4);
    bf16*  h2      = (bf16*) alloc((size_t)n * HID * 2);
    float* as2     = (float*)alloc((size_t)n * 4);
    float* ad2     = (float*)alloc((size_t)n * 4);
    float* outp    = (float*)d_out;

    int Ev = E, Etotv = Etot;
    void* args[] = {
        (void*)&ei, (void*)&Ev, (void*)&Etotv,
        (void*)&x, (void*)&pe, (void*)&W1,
        (void*)&a_s1, (void*)&a_d1, (void*)&b1,
        (void*)&W2, (void*)&a_s2, (void*)&a_d2, (void*)&b2,
        (void*)&cnt, (void*)&esrc,
        (void*)&h, (void*)&as1, (void*)&ad1,
        (void*)&h1,
        (void*)&h2, (void*)&as2, (void*)&ad2,
        (void*)&outp,
    };
    hipError_t err = hipLaunchCooperativeKernel((const void*)k_mega,
                                                dim3(GRIDB), dim3(256),
                                                args, 0, stream);
    if (err != hipSuccess) {
        (void)hipGetLastError();   // clear sticky error; deterministic fallback path
        int eblocks = (Etot + 255) / 256;
        k_zero   <<<n / (256 * 4), 256, 0, stream>>>((int4*)cnt);
        k_scatter<<<eblocks, 256, 0, stream>>>(ei, E, Etot, cnt, esrc);
        k_gemm1  <<<n / 16, 256, 0, stream>>>(x, pe, W1, a_s1, a_d1, h, as1, ad1);
        k_agg1   <<<n, 256, 0, stream>>>(cnt, esrc, h, as1, ad1, b1, h1);
        k_gemm2  <<<n / 16, 256, 0, stream>>>(h1, W2, a_s2, a_d2, h2, as2, ad2);
        k_agg2   <<<n / 4, 256, 0, stream>>>(cnt, esrc, h2, as2, ad2, b2, outp);
    }
}

// Round 10
// 180.677 us; speedup vs baseline: 2.9307x; 2.9307x over previous
//
#include <hip/hip_runtime.h>
#include <hip/hip_bf16.h>

typedef __hip_bfloat16 bf16;

#define N_NODES 16384
#define D_IN    128
#define HID     64
#define HEADS   4
#define F1      256   // HEADS*HID
#define SEQ     128
#define SLOTS   64    // fixed CSR capacity per node (P(deg>64) ~ 1e-12 for this graph)

__device__ __forceinline__ float wave_sum(float v) {
    #pragma unroll
    for (int o = 32; o > 0; o >>= 1) v += __shfl_xor(v, o, 64);
    return v;
}
__device__ __forceinline__ float wave_max(float v) {
    #pragma unroll
    for (int o = 32; o > 0; o >>= 1) v = fmaxf(v, __shfl_xor(v, o, 64));
    return v;
}
__device__ __forceinline__ float lrelu(float v) { return v > 0.f ? v : 0.2f * v; }
__device__ __forceinline__ float rdlane(float v, int l) {
    return __uint_as_float(__builtin_amdgcn_readlane(__float_as_uint(v), l));
}

// ---------------- D1: gemm1 (+PE, +logits) + cnt zeroing ----------------
// grid 1024, 16 rows/block, 4 rows/wave; x in registers, W1 streamed float4.
__global__ __launch_bounds__(256) void k_gemm1z(const float* __restrict__ x,
                                                const float* __restrict__ pe,
                                                const float* __restrict__ W1,
                                                const float* __restrict__ a_src1,
                                                const float* __restrict__ a_dst1,
                                                bf16* __restrict__ h,
                                                float* __restrict__ as1,
                                                float* __restrict__ ad1,
                                                int4* __restrict__ cntv) {
    int tid = threadIdx.x, lane = tid & 63, wv = tid >> 6;
    // zero cnt: 1024 blocks x 4 int4 = 16384 ints (scatter runs in a later dispatch)
    if (tid < 4) cntv[blockIdx.x * 4 + tid] = make_int4(0, 0, 0, 0);

    int base = blockIdx.x * 16;
    int j4 = lane * 4;
    float2 xr[4];
    #pragma unroll
    for (int i = 0; i < 4; i++) {
        int row = base + wv * 4 + i;
        float2 xa  = *(const float2*)(x  + (size_t)row * 128 + 2 * lane);
        float2 pea = *(const float2*)(pe + (size_t)(row & (SEQ - 1)) * 128 + 2 * lane);
        xr[i].x = xa.x * 11.313708499f + pea.x;
        xr[i].y = xa.y * 11.313708499f + pea.y;
    }
    float acc[4][4] = {};
    const float4* Wv = (const float4*)W1;   // Wv[k*64 + lane] == W1[k*256 + lane*4]
    #pragma unroll 4
    for (int k2 = 0; k2 < 64; k2++) {
        float4 w0 = Wv[(size_t)(2 * k2) * 64 + lane];
        float4 w1 = Wv[(size_t)(2 * k2 + 1) * 64 + lane];
        #pragma unroll
        for (int i = 0; i < 4; i++) {
            float a0 = rdlane(xr[i].x, k2);
            float a1 = rdlane(xr[i].y, k2);
            acc[i][0] += a0 * w0.x + a1 * w1.x;
            acc[i][1] += a0 * w0.y + a1 * w1.y;
            acc[i][2] += a0 * w0.z + a1 * w1.z;
            acc[i][3] += a0 * w0.w + a1 * w1.w;
        }
    }
    float4 asv = *(const float4*)(a_src1 + j4);
    float4 adv = *(const float4*)(a_dst1 + j4);
    #pragma unroll
    for (int i = 0; i < 4; i++) {
        int row = base + wv * 4 + i;
        union { bf16 b[4]; ushort4 u; } cv;
        cv.b[0] = __float2bfloat16(acc[i][0]);
        cv.b[1] = __float2bfloat16(acc[i][1]);
        cv.b[2] = __float2bfloat16(acc[i][2]);
        cv.b[3] = __float2bfloat16(acc[i][3]);
        *(ushort4*)(h + (size_t)row * 256 + j4) = cv.u;
        float vs = acc[i][0] * asv.x + acc[i][1] * asv.y + acc[i][2] * asv.z + acc[i][3] * asv.w;
        float vd = acc[i][0] * adv.x + acc[i][1] * adv.y + acc[i][2] * adv.z + acc[i][3] * adv.w;
        #pragma unroll
        for (int o = 1; o < 16; o <<= 1) {
            vs += __shfl_xor(vs, o);
            vd += __shfl_xor(vd, o);
        }
        if ((lane & 15) == 0) {
            as1[row * 4 + (lane >> 4)] = vs;
            ad1[row * 4 + (lane >> 4)] = vd;
        }
    }
}

// ---------------- D2: edge scatter ----------------
__global__ __launch_bounds__(256) void k_scatter(const int* __restrict__ ei, int E, int Etot,
                                                 int* __restrict__ cnt,
                                                 int* __restrict__ esrc) {
    int e = blockIdx.x * 256 + threadIdx.x;
    if (e >= Etot) return;
    int s, d;
    if (e < E) { s = ei[e]; d = ei[E + e]; }
    else       { s = e - E; d = s; }
    int pos = atomicAdd(&cnt[d], 1);
    if (pos < SLOTS) esrc[d * SLOTS + pos] = s;
}

// ---------------- D3: fused agg1 + gemm2 (+layer-2 logits) ----------------
// grid 2048, 8 nodes/block (8 blocks/CU -> full 32 waves/CU for the gather phase).
// agg1 phase: wave = head, loops 8 nodes, h1 rows land in LDS (8KB).
// gemm2 phase: 8 rows; wave computes 2 rows x 64 cols; W2 streamed coalesced.
__global__ __launch_bounds__(256) void k_agg1_gemm2(
        const int* __restrict__ cnt, const int* __restrict__ esrc,
        const bf16* __restrict__ h,
        const float* __restrict__ as1, const float* __restrict__ ad1,
        const float* __restrict__ b1,
        const float* __restrict__ W2,
        const float* __restrict__ a_src2, const float* __restrict__ a_dst2,
        bf16* __restrict__ h2, float* __restrict__ as2, float* __restrict__ ad2) {
    __shared__ float hs[8][256];
    int tid = threadIdx.x, lane = tid & 63, wv = tid >> 6;
    int dbase = blockIdx.x * 8;

    int eg = lane >> 3;   // edge slot within octet group
    int cg_ = lane & 7;   // channel group (8 channels, 16 B)
    const bf16* hbase = h + (size_t)wv * 64 + cg_ * 8;

    // ---- agg1 over 8 nodes ----
    for (int it = 0; it < 8; it++) {
        int d = dbase + it;
        int beg = d * SLOTS;
        int deg = min(cnt[d], SLOTS);
        float adw = ad1[d * 4 + wv];

        int s = 0; float ev = -1e30f;
        if (lane < deg) {
            s = esrc[beg + lane];
            ev = lrelu(as1[s * 4 + wv] + adw);
        }
        float mx = wave_max(ev);
        float t = (lane < deg) ? __expf(ev - mx) : 0.f;
        float den = wave_sum(t);

        float acc[8] = {0, 0, 0, 0, 0, 0, 0, 0};
        for (int sub = 0; sub < deg; sub += 32) {
            uint4 u[4]; float te[4];
            #pragma unroll
            for (int q = 0; q < 4; q++) {
                int e = sub + q * 8;
                int se = __shfl(s, e + eg);
                te[q] = __shfl(t, e + eg);
                if (e < deg) u[q] = *(const uint4*)(hbase + (size_t)se * 256);
                else         u[q] = make_uint4(0, 0, 0, 0);
            }
            #pragma unroll
            for (int q = 0; q < 4; q++) {
                acc[0] += te[q] * __uint_as_float(u[q].x << 16);
                acc[1] += te[q] * __uint_as_float(u[q].x & 0xffff0000u);
                acc[2] += te[q] * __uint_as_float(u[q].y << 16);
                acc[3] += te[q] * __uint_as_float(u[q].y & 0xffff0000u);
                acc[4] += te[q] * __uint_as_float(u[q].z << 16);
                acc[5] += te[q] * __uint_as_float(u[q].z & 0xffff0000u);
                acc[6] += te[q] * __uint_as_float(u[q].w << 16);
                acc[7] += te[q] * __uint_as_float(u[q].w & 0xffff0000u);
            }
        }
        #pragma unroll
        for (int j = 0; j < 8; j++) {
            acc[j] += __shfl_xor(acc[j], 8);
            acc[j] += __shfl_xor(acc[j], 16);
            acc[j] += __shfl_xor(acc[j], 32);
        }
        if (lane < 8) {
            float inv = 1.f / (den + 1e-16f);
            int cbase = wv * 64 + lane * 8;
            float o[8];
            #pragma unroll
            for (int j = 0; j < 8; j++) {
                float v = acc[j] * inv + b1[cbase + j];
                o[j] = v > 0.f ? v : (__expf(v) - 1.f);   // elu
            }
            float4* dst = (float4*)&hs[it][cbase];
            dst[0] = make_float4(o[0], o[1], o[2], o[3]);
            dst[1] = make_float4(o[4], o[5], o[6], o[7]);
        }
    }
    __syncthreads();

    // ---- gemm2 on the 8 rows in LDS ----
    {
        int r0 = wv * 2, r1 = wv * 2 + 1;
        const float4* h0v = (const float4*)&hs[r0][0];
        const float4* h1v = (const float4*)&hs[r1][0];
        float a0 = 0.f, a1 = 0.f;
        #pragma unroll 4
        for (int k4 = 0; k4 < 64; k4++) {
            float4 u0 = h0v[k4];
            float4 u1 = h1v[k4];
            const float* wp = W2 + (size_t)k4 * 256 + lane;   // W2[(k4*4+q)*64 + lane]
            float w0 = wp[0], w1 = wp[64], w2 = wp[128], w3 = wp[192];
            a0 += u0.x * w0 + u0.y * w1 + u0.z * w2 + u0.w * w3;
            a1 += u1.x * w0 + u1.y * w1 + u1.z * w2 + u1.w * w3;
        }
        float asj = a_src2[lane], adj = a_dst2[lane];
        int n0 = dbase + r0, n1 = dbase + r1;
        h2[(size_t)n0 * 64 + lane] = __float2bfloat16(a0);
        h2[(size_t)n1 * 64 + lane] = __float2bfloat16(a1);
        float va0 = wave_sum(a0 * asj);
        float vd0 = wave_sum(a0 * adj);
        float va1 = wave_sum(a1 * asj);
        float vd1 = wave_sum(a1 * adj);
        if (lane == 0) {
            as2[n0] = va0; ad2[n0] = vd0;
            as2[n1] = va1; ad2[n1] = vd1;
        }
    }
}

// ---------------- D4: agg2 -> out ----------------
__global__ __launch_bounds__(256) void k_agg2(const int* __restrict__ cnt,
                                              const int* __restrict__ esrc,
                                              const bf16* __restrict__ h2,
                                              const float* __restrict__ as2,
                                              const float* __restrict__ ad2,
                                              const float* __restrict__ b2v,
                                              float* __restrict__ out) {
    int tid = threadIdx.x, lane = tid & 63, wv = tid >> 6;
    int d = blockIdx.x * 4 + wv;
    int beg = d * SLOTS;
    int deg = min(cnt[d], SLOTS);
    float adw = ad2[d];
    int eg = lane >> 3, cg_ = lane & 7;
    const bf16* hbase = h2 + cg_ * 8;

    int s = 0; float ev = -1e30f;
    if (lane < deg) {
        s = esrc[beg + lane];
        ev = lrelu(as2[s] + adw);
    }
    float mx = wave_max(ev);
    float t = (lane < deg) ? __expf(ev - mx) : 0.f;
    float den = wave_sum(t);

    float acc[8] = {0, 0, 0, 0, 0, 0, 0, 0};
    for (int sub = 0; sub < deg; sub += 32) {
        uint4 u[4]; float te[4];
        #pragma unroll
        for (int q = 0; q < 4; q++) {
            int e = sub + q * 8;
            int se = __shfl(s, e + eg);
            te[q] = __shfl(t, e + eg);
            if (e < deg) u[q] = *(const uint4*)(hbase + (size_t)se * 64);
            else         u[q] = make_uint4(0, 0, 0, 0);
        }
        #pragma unroll
        for (int q = 0; q < 4; q++) {
            acc[0] += te[q] * __uint_as_float(u[q].x << 16);
            acc[1] += te[q] * __uint_as_float(u[q].x & 0xffff0000u);
            acc[2] += te[q] * __uint_as_float(u[q].y << 16);
            acc[3] += te[q] * __uint_as_float(u[q].y & 0xffff0000u);
            acc[4] += te[q] * __uint_as_float(u[q].z << 16);
            acc[5] += te[q] * __uint_as_float(u[q].z & 0xffff0000u);
            acc[6] += te[q] * __uint_as_float(u[q].w << 16);
            acc[7] += te[q] * __uint_as_float(u[q].w & 0xffff0000u);
        }
    }
    #pragma unroll
    for (int j = 0; j < 8; j++) {
        acc[j] += __shfl_xor(acc[j], 8);
        acc[j] += __shfl_xor(acc[j], 16);
        acc[j] += __shfl_xor(acc[j], 32);
    }
    if (lane < 8) {
        float inv = 1.f / (den + 1e-16f);
        int cbase = lane * 8;
        float o[8];
        #pragma unroll
        for (int j = 0; j < 8; j++) o[j] = acc[j] * inv + b2v[cbase + j];
        float4* dst = (float4*)(out + (size_t)d * 64 + cbase);
        dst[0] = make_float4(o[0], o[1], o[2], o[3]);
        dst[1] = make_float4(o[4], o[5], o[6], o[7]);
    }
}

extern "C" void kernel_launch(void* const* d_in, const int* in_sizes, int n_in,
                              void* d_out, int out_size, void* d_ws, size_t ws_size,
                              hipStream_t stream) {
    const float* x    = (const float*)d_in[0];
    const int*   ei   = (const int*)  d_in[1];
    const float* pe   = (const float*)d_in[2];
    const float* W1   = (const float*)d_in[3];
    const float* a_s1 = (const float*)d_in[4];
    const float* a_d1 = (const float*)d_in[5];
    const float* b1   = (const float*)d_in[6];
    const float* W2   = (const float*)d_in[7];
    const float* a_s2 = (const float*)d_in[8];
    const float* a_d2 = (const float*)d_in[9];
    const float* b2   = (const float*)d_in[10];

    const int E    = in_sizes[1] / 2;
    const int n    = N_NODES;
    const int Etot = E + n;

    // workspace carve-up (256B aligned)
    char* p = (char*)d_ws;
    auto alloc = [&](size_t bytes) -> void* {
        void* r = (void*)p;
        p += (bytes + 255) & ~(size_t)255;
        return r;
    };
    int*   cnt     = (int*)  alloc((size_t)n * 4);
    int*   esrc    = (int*)  alloc((size_t)n * SLOTS * 4);
    bf16*  h       = (bf16*) alloc((size_t)n * F1 * 2);
    float* as1     = (float*)alloc((size_t)n * HEADS * 4);
    float* ad1     = (float*)alloc((size_t)n * HEADS * 4);
    bf16*  h2      = (bf16*) alloc((size_t)n * HID * 2);
    float* as2     = (float*)alloc((size_t)n * 4);
    float* ad2     = (float*)alloc((size_t)n * 4);

    int eblocks = (Etot + 255) / 256;

    k_gemm1z    <<<n / 16, 256, 0, stream>>>(x, pe, W1, a_s1, a_d1, h, as1, ad1, (int4*)cnt);
    k_scatter   <<<eblocks, 256, 0, stream>>>(ei, E, Etot, cnt, esrc);
    k_agg1_gemm2<<<n / 8, 256, 0, stream>>>(cnt, esrc, h, as1, ad1, b1,
                                            W2, a_s2, a_d2, h2, as2, ad2);
    k_agg2      <<<n / 4, 256, 0, stream>>>(cnt, esrc, h2, as2, ad2, b2, (float*)d_out);
}